// Round 11
// baseline (121.389 us; speedup 1.0000x reference)
//
#include <hip/hip_runtime.h>
#include <stdint.h>

#define Bq 2
#define Tq 1024
#define Cq 1024
#define Hq 16
#define HDq 64

typedef unsigned int uint32;
typedef __attribute__((ext_vector_type(8))) short bf16x8;
typedef __attribute__((ext_vector_type(4))) float f32x4;

__device__ __forceinline__ short f2bf(float x) {
  union { float f; uint32 u; } v; v.f = x;
  uint32 r = (v.u + 0x7FFFu + ((v.u >> 16) & 1u)) >> 16;
  return (short)r;
}
__device__ __forceinline__ float bf2f(short h) {
  union { uint32 u; float f; } v; v.u = ((uint32)(unsigned short)h) << 16;
  return v.f;
}
__device__ __forceinline__ void gload16(const short* g, short* l) {
  __builtin_amdgcn_global_load_lds(
      (const __attribute__((address_space(1))) unsigned int*)g,
      (__attribute__((address_space(3))) unsigned int*)l, 16, 0, 0);
}
__device__ __forceinline__ f32x4 mfma16(bf16x8 a, bf16x8 b, f32x4 c) {
  return __builtin_amdgcn_mfma_f32_16x16x32_bf16(a, b, c, 0, 0, 0);
}

// ---- prep: pack x rows (blocks 0..1023) + split all 4 W mats (1024..2047) -
__global__ __launch_bounds__(256) void prep_all(
    const float* __restrict__ x,
    const float* __restrict__ Wq, const float* __restrict__ Wk,
    const float* __restrict__ Wv, const float* __restrict__ Wp,
    short* __restrict__ xp0, short* __restrict__ xp1, short* __restrict__ xp2,
    short* __restrict__ q0, short* __restrict__ q1, short* __restrict__ q2,
    short* __restrict__ k0, short* __restrict__ k1, short* __restrict__ k2,
    short* __restrict__ v0, short* __restrict__ p0, int N, int K)
{
  __shared__ float ws_[64][65];
  const int t = threadIdx.x;
  const int bid = blockIdx.x;
  const int KT = K >> 5;

  if (bid < 1024) {          // ---- pack_rows<3> on x ----
    const int tg = bid * 256 + t;
    const int lane = tg & 63, chunk = tg >> 6;
    const int mt = chunk / KT, kt = chunk % KT;
    const int m = mt * 16 + (lane & 15);
    const int k = kt * 32 + ((lane >> 4) << 3);
    float4 v0v = *reinterpret_cast<const float4*>(&x[(size_t)m * K + k]);
    float4 v1v = *reinterpret_cast<const float4*>(&x[(size_t)m * K + k + 4]);
    float a[8] = {v0v.x, v0v.y, v0v.z, v0v.w, v1v.x, v1v.y, v1v.z, v1v.w};
    bf16x8 o0, o1, o2;
#pragma unroll
    for (int j = 0; j < 8; ++j) {
      short h1 = f2bf(a[j]); o0[j] = h1;
      float r1 = a[j] - bf2f(h1);
      short h2 = f2bf(r1); o1[j] = h2;
      o2[j] = f2bf(r1 - bf2f(h2));
    }
    size_t off = (size_t)tg * 8;
    *reinterpret_cast<bf16x8*>(&xp0[off]) = o0;
    *reinterpret_cast<bf16x8*>(&xp1[off]) = o1;
    *reinterpret_cast<bf16x8*>(&xp2[off]) = o2;
    return;
  }
  const int id = bid - 1024;
  const int z = id >> 8, rem = id & 255;
  const int bxp = rem & 15, byp = rem >> 4;
  const float* W = (z == 0) ? Wq : (z == 1) ? Wk : (z == 2) ? Wv : Wp;
  short* P0 = (z == 0) ? q0 : (z == 1) ? k0 : (z == 2) ? v0 : p0;
  short* P1 = (z == 0) ? q1 : k1;
  short* P2 = (z == 0) ? q2 : k2;
  const bool ns3 = (z < 2);
  const int n0 = bxp * 64, k0g = byp * 64;
#pragma unroll
  for (int pass = 0; pass < 4; ++pass) {
    int f = pass * 256 + t;
    int r = f >> 4, c4 = (f & 15) << 2;
    float4 vv = *reinterpret_cast<const float4*>(&W[(size_t)(k0g + r) * N + n0 + c4]);
    ws_[r][c4 + 0] = vv.x; ws_[r][c4 + 1] = vv.y;
    ws_[r][c4 + 2] = vv.z; ws_[r][c4 + 3] = vv.w;
  }
  __syncthreads();
#pragma unroll
  for (int s = 0; s < 2; ++s) {
    int slot = s * 256 + t;
    int lane = slot & 63, u = slot >> 6;
    int ntl = u >> 1, ktl = u & 1;
    int nl = ntl * 16 + (lane & 15);
    int kb = ktl * 32 + ((lane >> 4) << 3);
    bf16x8 o0, o1, o2;
#pragma unroll
    for (int j = 0; j < 8; ++j) {
      float a = ws_[kb + j][nl];
      short h1 = f2bf(a); o0[j] = h1;
      float r1 = a - bf2f(h1);
      short h2 = f2bf(r1); o1[j] = h2;
      o2[j] = f2bf(r1 - bf2f(h2));
    }
    size_t nt = (size_t)bxp * 4 + ntl;
    size_t kt = (size_t)byp * 2 + ktl;
    size_t off = ((nt * KT + kt) * 64 + lane) * 8;
    *reinterpret_cast<bf16x8*>(&P0[off]) = o0;
    if (ns3) {
      *reinterpret_cast<bf16x8*>(&P1[off]) = o1;
      *reinterpret_cast<bf16x8*>(&P2[off]) = o2;
    }
  }
}

// ---- q/k GEMM (bf16x3, 6-term) + fused V half + rope+digit MFMA epilogue -
// BM=64: grid 1024 blocks, LDS 52 KB -> 3 blocks/CU co-resident (TLP).
// by = head. z=0: q digits + V cols [0,32); z=1: k digits + V cols [32,64).
__global__ __launch_bounds__(256) void gemm_qk_digits(
    const short* __restrict__ A0, const short* __restrict__ A1, const short* __restrict__ A2,
    const short* __restrict__ Bq0, const short* __restrict__ Bq1, const short* __restrict__ Bq2,
    const short* __restrict__ Bk0, const short* __restrict__ Bk1, const short* __restrict__ Bk2,
    const short* __restrict__ Bv0,
    const float* __restrict__ cosT, const float* __restrict__ sinT,
    const float* __restrict__ Wdq, const float* __restrict__ Wdk,
    uint8_t* __restrict__ dqb, uint8_t* __restrict__ dkb,
    short* __restrict__ PVout, int K)
{
  constexpr int BUF = 26 * 512;               // 12 A + 12 Bqk + 2 Bv chunks
  __shared__ short sm[2 * BUF];               // 53248 B
  const int t = threadIdx.x, wid = t >> 6, lane = t & 63;
  const int wr = wid >> 1, wc = wid & 1;
  const int g4 = lane >> 4, r15 = lane & 15;
  const int bx = blockIdx.x, by = blockIdx.y, z = blockIdx.z;
  const int KT = K >> 5;
  const short* Ap[3] = {A0, A1, A2};
  const short* Bp[3];
  if (z == 0) { Bp[0] = Bq0; Bp[1] = Bq1; Bp[2] = Bq2; }
  else        { Bp[0] = Bk0; Bp[1] = Bk1; Bp[2] = Bk2; }

  // 26 staging chunks over 4 waves: 7,7,6,6
  const int cnt = (wid < 2) ? 7 : 6;
  const int cbase = (wid < 2) ? wid * 7 : 14 + (wid - 2) * 6;
  const short* gb[7]; int lof[7];
#pragma unroll
  for (int i = 0; i < 7; ++i) {
    int c = cbase + i;
    if (i < cnt) {
      if (c < 12) {
        int p = c >> 2, mtl = c & 3;
        gb[i] = Ap[p] + ((size_t)(bx * 4 + mtl) * KT * 512 + lane * 8);
      } else if (c < 24) {
        int c2 = c - 12; int p = c2 >> 2, ntl = c2 & 3;
        gb[i] = Bp[p] + ((size_t)(by * 4 + ntl) * KT * 512 + lane * 8);
      } else {
        gb[i] = Bv0 + ((size_t)(by * 4 + z * 2 + (c - 24)) * KT * 512 + lane * 8);
      }
      lof[i] = c * 512;                       // wave-uniform base; HW adds lane*16B
    }
  }

  f32x4 acc[2][2], vacc[2];
#pragma unroll
  for (int fr = 0; fr < 2; ++fr) {
#pragma unroll
    for (int fc = 0; fc < 2; ++fc) acc[fr][fc] = (f32x4){0.f, 0.f, 0.f, 0.f};
    vacc[fr] = (f32x4){0.f, 0.f, 0.f, 0.f};
  }

#pragma unroll
  for (int i = 0; i < 7; ++i)
    if (i < cnt) gload16(gb[i], &sm[lof[i]]);

  int cur = 0;
  for (int kt = 0; kt < KT; ++kt) {
    __syncthreads();                          // proven 2-buffer semantics
    if (kt + 1 < KT) {
#pragma unroll
      for (int i = 0; i < 7; ++i)
        if (i < cnt)
          gload16(gb[i] + (size_t)(kt + 1) * 512, &sm[(cur ^ 1) * BUF + lof[i]]);
    }
    const short* sa = &sm[cur * BUF];
    bf16x8 af[3][2], bfr[3][2];
#pragma unroll
    for (int p = 0; p < 3; ++p)
#pragma unroll
      for (int fr = 0; fr < 2; ++fr)
        af[p][fr] = *reinterpret_cast<const bf16x8*>(sa + (p * 4 + wr * 2 + fr) * 512 + lane * 8);
#pragma unroll
    for (int p = 0; p < 3; ++p)
#pragma unroll
      for (int fc = 0; fc < 2; ++fc)
        bfr[p][fc] = *reinterpret_cast<const bf16x8*>(sa + (12 + p * 4 + wc * 2 + fc) * 512 + lane * 8);
    bf16x8 bv = *reinterpret_cast<const bf16x8*>(sa + (24 + wc) * 512 + lane * 8);
#pragma unroll
    for (int fr = 0; fr < 2; ++fr) {
#pragma unroll
      for (int fc = 0; fc < 2; ++fc) {
        acc[fr][fc] = mfma16(af[0][fr], bfr[0][fc], acc[fr][fc]);
        acc[fr][fc] = mfma16(af[0][fr], bfr[1][fc], acc[fr][fc]);
        acc[fr][fc] = mfma16(af[1][fr], bfr[0][fc], acc[fr][fc]);
        acc[fr][fc] = mfma16(af[1][fr], bfr[1][fc], acc[fr][fc]);
        acc[fr][fc] = mfma16(af[0][fr], bfr[2][fc], acc[fr][fc]);
        acc[fr][fc] = mfma16(af[2][fr], bfr[0][fc], acc[fr][fc]);
      }
      vacc[fr] = mfma16(af[0][fr], bv, vacc[fr]);
    }
    cur ^= 1;
  }

  // ---- epilogue (64 rows, one pass) --------------------------------------
  __syncthreads();   // all LDS reads of sm done; repurpose
  const float* Wd = z ? Wdk : Wdq;
  bf16x8 bw0[2], bw1[2], bw2[2];
#pragma unroll
  for (int kt2 = 0; kt2 < 2; ++kt2) {
#pragma unroll
    for (int j = 0; j < 8; ++j) {
      float wv = (r15 < 8) ? Wd[(size_t)(kt2 * 32 + g4 * 8 + j) * 8 + r15] : 0.f;
      short h1 = f2bf(wv); float rr = wv - bf2f(h1);
      short h2 = f2bf(rr); short h3 = f2bf(rr - bf2f(h2));
      bw0[kt2][j] = h1; bw1[kt2][j] = h2; bw2[kt2][j] = h3;
    }
  }
  float* accs = reinterpret_cast<float*>(sm);   // [64][65] f32 = 8320 shorts
  short* RA  = sm + 8320;                       // 3 planes x 4096 shorts
  short* vsv = sm + 8320 + 12288;               // [64][34] = 2176 shorts
  uint8_t* dst = z ? dkb : dqb;

#pragma unroll
  for (int fr = 0; fr < 2; ++fr)
#pragma unroll
    for (int fc = 0; fc < 2; ++fc)
#pragma unroll
      for (int rg = 0; rg < 4; ++rg) {
        int row = wr * 32 + fr * 16 + g4 * 4 + rg;
        int col = wc * 32 + fc * 16 + r15;
        accs[row * 65 + col] = acc[fr][fc][rg];
      }
#pragma unroll
  for (int fr = 0; fr < 2; ++fr)
#pragma unroll
    for (int rg = 0; rg < 4; ++rg) {
      int row = wr * 32 + fr * 16 + g4 * 4 + rg;
      vsv[row * 34 + wc * 16 + r15] = f2bf(vacc[fr][rg]);
    }
  __syncthreads();

  {  // emit packed V chunks: 4 chunks, 256 threads (cols z*32..z*32+31)
    const int bb = bx >> 4;
    int lp = t & 63, ch = t >> 6;              // ch 0..3
    int kl = ch & 1, ntv = ch >> 1;
    bf16x8 o;
#pragma unroll
    for (int j = 0; j < 8; ++j)
      o[j] = vsv[(kl * 32 + (lp >> 4) * 8 + j) * 34 + ntv * 16 + (lp & 15)];
    int kTg = (bx & 15) * 2 + kl;
    int ntg = z * 2 + ntv;
    size_t flat = ((((size_t)(bb * Hq + by) * 4 + ntg) * 32 + kTg) * 64 + lp) * 8;
    *reinterpret_cast<bf16x8*>(&PVout[flat]) = o;
  }

  {  // rope + bf16x3 split -> A-fragment planes (64 rows)
    const int row = t >> 2, db = t & 3;
    const int mt = row >> 4;
    const int lfr = (row & 15) | (db << 4);
    const int tg = (bx * 64 + row) & (Tq - 1);
#pragma unroll
    for (int i = 0; i < 8; ++i) {
      int d = db * 8 + i;
      float q1 = accs[row * 65 + d], q2 = accs[row * 65 + d + 32];
      float c = cosT[tg * 32 + d], s = sinT[tg * 32 + d];
      float r1 = q1 * c + q2 * s;
      float r2 = q2 * c - q1 * s;   // rms scale positive -> sign-invariant, skipped
      int i0 = ((mt * 2 + 0) * 64 + lfr) * 8 + i;
      int i1 = ((mt * 2 + 1) * 64 + lfr) * 8 + i;
      short h1 = f2bf(r1); float rr = r1 - bf2f(h1);
      short h2 = f2bf(rr); short h3 = f2bf(rr - bf2f(h2));
      RA[i0] = h1; RA[4096 + i0] = h2; RA[8192 + i0] = h3;
      h1 = f2bf(r2); rr = r2 - bf2f(h1);
      h2 = f2bf(rr); h3 = f2bf(rr - bf2f(h2));
      RA[i1] = h1; RA[4096 + i1] = h2; RA[8192 + i1] = h3;
    }
  }
  __syncthreads();
  {  // 12 MFMAs per wave: digits for 16 rows; ballot -> bytes
    const int mt = wid;
    f32x4 dacc = (f32x4){0.f, 0.f, 0.f, 0.f};
#pragma unroll
    for (int kt2 = 0; kt2 < 2; ++kt2) {
      int base = ((mt * 2 + kt2) * 64 + lane) * 8;
      bf16x8 ra0 = *reinterpret_cast<const bf16x8*>(&RA[base]);
      bf16x8 ra1 = *reinterpret_cast<const bf16x8*>(&RA[4096 + base]);
      bf16x8 ra2 = *reinterpret_cast<const bf16x8*>(&RA[8192 + base]);
      dacc = mfma16(ra0, bw0[kt2], dacc);
      dacc = mfma16(ra0, bw1[kt2], dacc);
      dacc = mfma16(ra1, bw0[kt2], dacc);
      dacc = mfma16(ra1, bw1[kt2], dacc);
      dacc = mfma16(ra0, bw2[kt2], dacc);
      dacc = mfma16(ra2, bw0[kt2], dacc);
    }
#pragma unroll
    for (int rg = 0; rg < 4; ++rg) {
      unsigned long long m = __ballot(dacc[rg] > 0.f);
      if (lane == 0) {
#pragma unroll
        for (int g2 = 0; g2 < 4; ++g2) {
          int rowg = bx * 64 + mt * 16 + g2 * 4 + rg;
          uint8_t byte = (uint8_t)((m >> (g2 * 16)) & 0xFFu);
          dst[((size_t)(rowg >> 10) * Hq + by) * Tq + (rowg & (Tq - 1))] = byte;
        }
      }
    }
  }
}

// ---- MFMA ultrametric causal attention, writes yp packed-A directly ------
__global__ __launch_bounds__(256) void attn_mfma(
    const short* __restrict__ PV, const uint8_t* __restrict__ dqb,
    const uint8_t* __restrict__ dkb, short* __restrict__ yp)
{
  __shared__ short vbuf[2][4][2][512];
  __shared__ __align__(16) uint32 dks4[256];
  __shared__ float den_lds[64];
  __shared__ short ys[64 * 66];
  const int t = threadIdx.x, wid = t >> 6, lane = t & 63;
  const int r = lane & 15, g = lane >> 4;
  const int qt = blockIdx.x, h = blockIdx.y, b = blockIdx.z;
  const int bh = b * Hq + h;
  const short* pvb = PV + ((size_t)bh * 4 + wid) * 32 * 512 + lane * 8;

  {
    const uint32* src4 = (const uint32*)(dkb + (size_t)bh * Tq);
    if (t < (qt + 1) * 16) dks4[t] = src4[t];
  }
  const uint8_t* dq_tile = dqb + (size_t)bh * Tq + qt * 64;
  uint32 myq[4];
#pragma unroll
  for (int mt = 0; mt < 4; ++mt) myq[mt] = dq_tile[mt * 16 + r];

#pragma unroll
  for (int ks = 0; ks < 2; ++ks)
    gload16(pvb + (size_t)ks * 512, &vbuf[0][wid][ks][0]);

  f32x4 acc[4];
#pragma unroll
  for (int mt = 0; mt < 4; ++mt) acc[mt] = (f32x4){0.f, 0.f, 0.f, 0.f};
  uint32 den_i = 0;

  auto tile = [&](int kt, int db, bool MASK) {
    bf16x8 bfr[2];
#pragma unroll
    for (int ks = 0; ks < 2; ++ks)
      bfr[ks] = *reinterpret_cast<const bf16x8*>(&vbuf[db][wid][ks][lane * 8]);
    unsigned long long d8[2];
#pragma unroll
    for (int ks = 0; ks < 2; ++ks)
      d8[ks] = *reinterpret_cast<const unsigned long long*>(
          (const char*)dks4 + kt * 64 + ks * 32 + g * 8);
#pragma unroll
    for (int mt = 0; mt < 4; ++mt) {
      const uint32 dq = myq[mt];
      const int qrow = mt * 16 + r;
#pragma unroll
      for (int ks = 0; ks < 2; ++ks) {
        const int kbase = ks * 32 + g * 8;
        uint32 parts[4];
#pragma unroll
        for (int jj = 0; jj < 4; ++jj) {
          uint32 b0 = (uint32)(d8[ks] >> (16 * jj)) & 0xFFu;
          uint32 b1 = (uint32)(d8[ks] >> (16 * jj + 8)) & 0xFFu;
          uint32 e0 = (uint32)__builtin_ctz((dq ^ b0) | 0x100u);
          uint32 e1 = (uint32)__builtin_ctz((dq ^ b1) | 0x100u);
          uint32 w0 = 0x3F80u + (e0 << 7);
          uint32 w1 = 0x3F80u + (e1 << 7);
          if (MASK) {
            if (kbase + 2 * jj     > qrow) w0 = 0;
            if (kbase + 2 * jj + 1 > qrow) w1 = 0;
          }
          if (mt == wid) {
            den_i += (w0 ? (1u << e0) : 0u);
            den_i += (w1 ? (1u << e1) : 0u);
          }
          parts[jj] = w0 | (w1 << 16);
        }
        union { uint32 u[4]; bf16x8 v8; } cv;
        cv.u[0] = parts[0]; cv.u[1] = parts[1];
        cv.u[2] = parts[2]; cv.u[3] = parts[3];
        acc[mt] = mfma16(cv.v8, bfr[ks], acc[mt]);
      }
    }
  };

  int cur = 0;
  for (int kt = 0; kt < qt; ++kt) {
    __syncthreads();
#pragma unroll
    for (int ks = 0; ks < 2; ++ks)
      gload16(pvb + (size_t)((kt + 1) * 2 + ks) * 512, &vbuf[cur ^ 1][wid][ks][0]);
    tile(kt, cur, false);
    cur ^= 1;
  }
  __syncthreads();
  tile(qt, cur, true);

  den_i += (uint32)__shfl_xor((int)den_i, 16, 64);
  den_i += (uint32)__shfl_xor((int)den_i, 32, 64);
  if (lane < 16) den_lds[wid * 16 + lane] = (float)den_i;
  __syncthreads();

  const int dglob = wid * 16 + r;
#pragma unroll
  for (int mt = 0; mt < 4; ++mt)
#pragma unroll
    for (int rg = 0; rg < 4; ++rg) {
      int qloc = mt * 16 + g * 4 + rg;
      ys[qloc * 66 + dglob] = f2bf(acc[mt][rg] / fmaxf(den_lds[qloc], 1e-9f));
    }
  __syncthreads();
#pragma unroll
  for (int it = 0; it < 2; ++it) {
    int slot = it * 256 + t;
    int lp = slot & 63, ch = slot >> 6;
    int kh = ch & 1, mtl = ch >> 1;
    int fbase = kh * 32 + (lp >> 4) * 8;
    bf16x8 o;
#pragma unroll
    for (int j = 0; j < 8; ++j) o[j] = ys[(mtl * 16 + (lp & 15)) * 66 + fbase + j];
    int mtg = b * 64 + qt * 4 + mtl;
    int ktg = h * 2 + kh;
    size_t flat = ((size_t)mtg * 32 + ktg) * 512 + (size_t)lp * 8;
    *reinterpret_cast<bf16x8*>(&yp[flat]) = o;
  }
}

// ---- proj GEMM: 64x64 tile, BK=64 stages, 512 blocks (2/CU) --------------
__global__ __launch_bounds__(256) void gemm_proj(
    const short* __restrict__ A0, const short* __restrict__ B0,
    float* __restrict__ C, int M, int N, int K)
{
  constexpr int BUF = 16 * 512;
  __shared__ short sm[2 * BUF];               // 32 KB
  const int t = threadIdx.x, wid = t >> 6, lane = t & 63;
  const int bx = blockIdx.x, by = blockIdx.y;
  const int KT = K >> 5;                      // 32
  const int NST = KT >> 1;                    // 16 stages of BK=64

  const short* gb[4]; int lof[4];
#pragma unroll
  for (int i = 0; i < 4; ++i) {
    int c = wid * 4 + i;
    if (c < 8) {
      int mt = bx * 4 + (c >> 1), kt = c & 1;
      gb[i] = A0 + ((size_t)(mt * KT + kt) * 64 + lane) * 8;
    } else {
      int c2 = c - 8;
      int nt = by * 4 + (c2 >> 1), kt = c2 & 1;
      gb[i] = B0 + ((size_t)(nt * KT + kt) * 64 + lane) * 8;
    }
    lof[i] = c * 512;
  }

  f32x4 acc[4];
#pragma unroll
  for (int nt = 0; nt < 4; ++nt) acc[nt] = (f32x4){0.f, 0.f, 0.f, 0.f};

#pragma unroll
  for (int i = 0; i < 4; ++i) gload16(gb[i], &sm[lof[i]]);

  int cur = 0;
  for (int s = 0; s < NST; ++s) {
    __syncthreads();
    if (s + 1 < NST) {
#pragma unroll
      for (int i = 0; i < 4; ++i)
        gload16(gb[i] + (size_t)(s + 1) * 1024, &sm[(cur ^ 1) * BUF + lof[i]]);
    }
    const short* sa = &sm[cur * BUF];
#pragma unroll
    for (int kt2 = 0; kt2 < 2; ++kt2) {
      bf16x8 af = *reinterpret_cast<const bf16x8*>(sa + (wid * 2 + kt2) * 512 + lane * 8);
#pragma unroll
      for (int nt = 0; nt < 4; ++nt) {
        bf16x8 bf_ = *reinterpret_cast<const bf16x8*>(sa + (8 + nt * 2 + kt2) * 512 + lane * 8);
        acc[nt] = mfma16(af, bf_, acc[nt]);
      }
    }
    cur ^= 1;
  }

  const int rb = bx * 64 + wid * 16 + ((lane >> 4) << 2);
  const int cb = by * 64 + (lane & 15);
#pragma unroll
  for (int nt = 0; nt < 4; ++nt)
#pragma unroll
    for (int rg = 0; rg < 4; ++rg)
      C[(size_t)(rb + rg) * N + cb + nt * 16] = acc[nt][rg];
}

// --------------------------------------------------------------------------
extern "C" void kernel_launch(void* const* d_in, const int* in_sizes, int n_in,
                              void* d_out, int out_size, void* d_ws, size_t ws_size,
                              hipStream_t stream)
{
  const float* x    = (const float*)d_in[0];
  const float* cosT = (const float*)d_in[1];
  const float* sinT = (const float*)d_in[2];
  const float* Wq   = (const float*)d_in[3];
  const float* Wk   = (const float*)d_in[4];
  const float* Wv   = (const float*)d_in[5];
  const float* Wpr  = (const float*)d_in[6];
  const float* Wdq  = (const float*)d_in[7];
  const float* Wdk  = (const float*)d_in[8];
  float* out = (float*)d_out;

  const size_t MB = (size_t)1 << 20;
  char* w = (char*)d_ws;
  short* PV  = (short*)(w + 0 * MB);
  short* yp  = (short*)(w + 8 * MB);
  short* xp0 = (short*)(w + 24 * MB);
  short* xp1 = (short*)(w + 28 * MB);
  short* xp2 = (short*)(w + 32 * MB);
  short* wq0 = (short*)(w + 36 * MB);
  short* wq1 = (short*)(w + 38 * MB);
  short* wq2 = (short*)(w + 40 * MB);
  short* wk0 = (short*)(w + 42 * MB);
  short* wk1 = (short*)(w + 44 * MB);
  short* wk2 = (short*)(w + 46 * MB);
  short* wv_ = (short*)(w + 48 * MB);
  short* wp_ = (short*)(w + 50 * MB);
  uint8_t* dqb = (uint8_t*)(w + 52 * MB);
  uint8_t* dkb = dqb + (size_t)Bq * Hq * Tq;

  const int M = Bq * Tq, N = Cq, K = Cq;

  prep_all<<<2048, 256, 0, stream>>>(
      x, Wq, Wk, Wv, Wpr, xp0, xp1, xp2,
      wq0, wq1, wq2, wk0, wk1, wk2, wv_, wp_, N, K);

  gemm_qk_digits<<<dim3(32, 16, 2), 256, 0, stream>>>(
      xp0, xp1, xp2, wq0, wq1, wq2, wk0, wk1, wk2, wv_,
      cosT, sinT, Wdq, Wdk, dqb, dkb, PV, K);

  attn_mfma<<<dim3(16, 16, 2), 256, 0, stream>>>(PV, dqb, dkb, yp);

  gemm_proj<<<dim3(32, 16), 256, 0, stream>>>(yp, wp_, out, M, N, K);
}

// Round 12
// 109.924 us; speedup vs baseline: 1.1043x; 1.1043x over previous
//
#include <hip/hip_runtime.h>
#include <stdint.h>

#define Bq 2
#define Tq 1024
#define Cq 1024
#define Hq 16
#define HDq 64

typedef unsigned int uint32;
typedef __attribute__((ext_vector_type(8))) short bf16x8;
typedef __attribute__((ext_vector_type(4))) float f32x4;

__device__ __forceinline__ short f2bf(float x) {
  union { float f; uint32 u; } v; v.f = x;
  uint32 r = (v.u + 0x7FFFu + ((v.u >> 16) & 1u)) >> 16;
  return (short)r;
}
__device__ __forceinline__ float bf2f(short h) {
  union { uint32 u; float f; } v; v.u = ((uint32)(unsigned short)h) << 16;
  return v.f;
}
__device__ __forceinline__ void gload16(const short* g, short* l) {
  __builtin_amdgcn_global_load_lds(
      (const __attribute__((address_space(1))) unsigned int*)g,
      (__attribute__((address_space(3))) unsigned int*)l, 16, 0, 0);
}
__device__ __forceinline__ f32x4 mfma16(bf16x8 a, bf16x8 b, f32x4 c) {
  return __builtin_amdgcn_mfma_f32_16x16x32_bf16(a, b, c, 0, 0, 0);
}

// ---- prep: pack x rows (blocks 0..1023) + split all 4 W mats (1024..2047) -
__global__ __launch_bounds__(256) void prep_all(
    const float* __restrict__ x,
    const float* __restrict__ Wq, const float* __restrict__ Wk,
    const float* __restrict__ Wv, const float* __restrict__ Wp,
    short* __restrict__ xp0, short* __restrict__ xp1, short* __restrict__ xp2,
    short* __restrict__ q0, short* __restrict__ q1, short* __restrict__ q2,
    short* __restrict__ k0, short* __restrict__ k1, short* __restrict__ k2,
    short* __restrict__ v0, short* __restrict__ p0, int N, int K)
{
  __shared__ float ws_[64][65];
  const int t = threadIdx.x;
  const int bid = blockIdx.x;
  const int KT = K >> 5;

  if (bid < 1024) {          // ---- pack_rows<3> on x ----
    const int tg = bid * 256 + t;
    const int lane = tg & 63, chunk = tg >> 6;
    const int mt = chunk / KT, kt = chunk % KT;
    const int m = mt * 16 + (lane & 15);
    const int k = kt * 32 + ((lane >> 4) << 3);
    float4 v0v = *reinterpret_cast<const float4*>(&x[(size_t)m * K + k]);
    float4 v1v = *reinterpret_cast<const float4*>(&x[(size_t)m * K + k + 4]);
    float a[8] = {v0v.x, v0v.y, v0v.z, v0v.w, v1v.x, v1v.y, v1v.z, v1v.w};
    bf16x8 o0, o1, o2;
#pragma unroll
    for (int j = 0; j < 8; ++j) {
      short h1 = f2bf(a[j]); o0[j] = h1;
      float r1 = a[j] - bf2f(h1);
      short h2 = f2bf(r1); o1[j] = h2;
      o2[j] = f2bf(r1 - bf2f(h2));
    }
    size_t off = (size_t)tg * 8;
    *reinterpret_cast<bf16x8*>(&xp0[off]) = o0;
    *reinterpret_cast<bf16x8*>(&xp1[off]) = o1;
    *reinterpret_cast<bf16x8*>(&xp2[off]) = o2;
    return;
  }
  const int id = bid - 1024;
  const int z = id >> 8, rem = id & 255;
  const int bxp = rem & 15, byp = rem >> 4;
  const float* W = (z == 0) ? Wq : (z == 1) ? Wk : (z == 2) ? Wv : Wp;
  short* P0 = (z == 0) ? q0 : (z == 1) ? k0 : (z == 2) ? v0 : p0;
  short* P1 = (z == 0) ? q1 : k1;
  short* P2 = (z == 0) ? q2 : k2;
  const bool ns3 = (z < 2);
  const int n0 = bxp * 64, k0g = byp * 64;
#pragma unroll
  for (int pass = 0; pass < 4; ++pass) {
    int f = pass * 256 + t;
    int r = f >> 4, c4 = (f & 15) << 2;
    float4 vv = *reinterpret_cast<const float4*>(&W[(size_t)(k0g + r) * N + n0 + c4]);
    ws_[r][c4 + 0] = vv.x; ws_[r][c4 + 1] = vv.y;
    ws_[r][c4 + 2] = vv.z; ws_[r][c4 + 3] = vv.w;
  }
  __syncthreads();
#pragma unroll
  for (int s = 0; s < 2; ++s) {
    int slot = s * 256 + t;
    int lane = slot & 63, u = slot >> 6;
    int ntl = u >> 1, ktl = u & 1;
    int nl = ntl * 16 + (lane & 15);
    int kb = ktl * 32 + ((lane >> 4) << 3);
    bf16x8 o0, o1, o2;
#pragma unroll
    for (int j = 0; j < 8; ++j) {
      float a = ws_[kb + j][nl];
      short h1 = f2bf(a); o0[j] = h1;
      float r1 = a - bf2f(h1);
      short h2 = f2bf(r1); o1[j] = h2;
      o2[j] = f2bf(r1 - bf2f(h2));
    }
    size_t nt = (size_t)bxp * 4 + ntl;
    size_t kt = (size_t)byp * 2 + ktl;
    size_t off = ((nt * KT + kt) * 64 + lane) * 8;
    *reinterpret_cast<bf16x8*>(&P0[off]) = o0;
    if (ns3) {
      *reinterpret_cast<bf16x8*>(&P1[off]) = o1;
      *reinterpret_cast<bf16x8*>(&P2[off]) = o2;
    }
  }
}

// ---- q/k GEMM (bf16x3) + fused V half + rope+digit MFMA epilogue ---------
// by = head. z=0: q digits + V cols [0,32); z=1: k digits + V cols [32,64).
__global__ __launch_bounds__(256) void gemm_qk_digits(
    const short* __restrict__ A0, const short* __restrict__ A1, const short* __restrict__ A2,
    const short* __restrict__ Bq0, const short* __restrict__ Bq1, const short* __restrict__ Bq2,
    const short* __restrict__ Bk0, const short* __restrict__ Bk1, const short* __restrict__ Bk2,
    const short* __restrict__ Bv0,
    const float* __restrict__ cosT, const float* __restrict__ sinT,
    const float* __restrict__ Wdq, const float* __restrict__ Wdk,
    uint8_t* __restrict__ dqb, uint8_t* __restrict__ dkb,
    short* __restrict__ PVout, int K)
{
  constexpr int NS = 3;
  constexpr int BUF = 38 * 512;               // 24 A + 12 Bqk + 2 Bv chunks
  __shared__ short sm[2 * BUF];               // 77824 B
  const int t = threadIdx.x, wid = t >> 6, lane = t & 63;
  const int wr = wid >> 1, wc = wid & 1;
  const int g4 = lane >> 4, r15 = lane & 15;
  const int bx = blockIdx.x, by = blockIdx.y, z = blockIdx.z;
  const int KT = K >> 5;
  const short* Ap[3] = {A0, A1, A2};
  const short* Bp[3];
  if (z == 0) { Bp[0] = Bq0; Bp[1] = Bq1; Bp[2] = Bq2; }
  else        { Bp[0] = Bk0; Bp[1] = Bk1; Bp[2] = Bk2; }

  const short* gb[9]; int lof[9];
#pragma unroll
  for (int i = 0; i < 9; ++i) {
    int c = wid * 9 + i;
    if (c < 24) {
      int p = c >> 3, mtl = c & 7;
      gb[i] = Ap[p] + ((size_t)(bx * 8 + mtl) * KT * 512 + lane * 8);
      lof[i] = c * 512;
    } else {
      int c2 = c - 24; int p = c2 >> 2, ntl = c2 & 3;
      gb[i] = Bp[p] + ((size_t)(by * 4 + ntl) * KT * 512 + lane * 8);
      lof[i] = (24 + c2) * 512;
    }
  }
  const short* gbv = nullptr; int lofv = 0;
  if (wid < 2) {
    gbv = Bv0 + ((size_t)(by * 4 + z * 2 + wid) * KT * 512 + lane * 8);
    lofv = (36 + wid) * 512;
  }

  f32x4 acc[4][2], vacc[4];
#pragma unroll
  for (int fr = 0; fr < 4; ++fr) {
#pragma unroll
    for (int fc = 0; fc < 2; ++fc) acc[fr][fc] = (f32x4){0.f, 0.f, 0.f, 0.f};
    vacc[fr] = (f32x4){0.f, 0.f, 0.f, 0.f};
  }

#pragma unroll
  for (int i = 0; i < 9; ++i) gload16(gb[i], &sm[lof[i]]);
  if (wid < 2) gload16(gbv, &sm[lofv]);

  int cur = 0;
  for (int kt = 0; kt < KT; ++kt) {
    __syncthreads();
    if (kt + 1 < KT) {
#pragma unroll
      for (int i = 0; i < 9; ++i)
        gload16(gb[i] + (size_t)(kt + 1) * 512, &sm[(cur ^ 1) * BUF + lof[i]]);
      if (wid < 2)
        gload16(gbv + (size_t)(kt + 1) * 512, &sm[(cur ^ 1) * BUF + lofv]);
    }
    const short* sa = &sm[cur * BUF];
    const short* sbb = sa + 24 * 512;
    bf16x8 af[NS][4], bfr[NS][2];
#pragma unroll
    for (int p = 0; p < NS; ++p)
#pragma unroll
      for (int fr = 0; fr < 4; ++fr)
        af[p][fr] = *reinterpret_cast<const bf16x8*>(sa + (p * 8 + wr * 4 + fr) * 512 + lane * 8);
#pragma unroll
    for (int p = 0; p < NS; ++p)
#pragma unroll
      for (int fc = 0; fc < 2; ++fc)
        bfr[p][fc] = *reinterpret_cast<const bf16x8*>(sbb + (p * 4 + wc * 2 + fc) * 512 + lane * 8);
    bf16x8 bv = *reinterpret_cast<const bf16x8*>(sa + (36 + wc) * 512 + lane * 8);
#pragma unroll
    for (int fr = 0; fr < 4; ++fr) {
#pragma unroll
      for (int fc = 0; fc < 2; ++fc) {
        acc[fr][fc] = mfma16(af[0][fr], bfr[0][fc], acc[fr][fc]);
        acc[fr][fc] = mfma16(af[0][fr], bfr[1][fc], acc[fr][fc]);
        acc[fr][fc] = mfma16(af[1][fr], bfr[0][fc], acc[fr][fc]);
        acc[fr][fc] = mfma16(af[1][fr], bfr[1][fc], acc[fr][fc]);
        acc[fr][fc] = mfma16(af[0][fr], bfr[2][fc], acc[fr][fc]);
        acc[fr][fc] = mfma16(af[2][fr], bfr[0][fc], acc[fr][fc]);
      }
      vacc[fr] = mfma16(af[0][fr], bv, vacc[fr]);
    }
    cur ^= 1;
  }

  // ---- epilogue ----------------------------------------------------------
  __syncthreads();   // all LDS reads of sm done; repurpose
  const float* Wd = z ? Wdk : Wdq;
  bf16x8 bw0[2], bw1[2], bw2[2];
#pragma unroll
  for (int kt2 = 0; kt2 < 2; ++kt2) {
#pragma unroll
    for (int j = 0; j < 8; ++j) {
      float wv = (r15 < 8) ? Wd[(size_t)(kt2 * 32 + g4 * 8 + j) * 8 + r15] : 0.f;
      short h1 = f2bf(wv); float rr = wv - bf2f(h1);
      short h2 = f2bf(rr); short h3 = f2bf(rr - bf2f(h2));
      bw0[kt2][j] = h1; bw1[kt2][j] = h2; bw2[kt2][j] = h3;
    }
  }
  float* accs = reinterpret_cast<float*>(sm);   // [128][65] f32 (16640 shorts)
  short* RA  = sm + 16640;                      // 3 x 4096 shorts
  short* vsv = sm + 28928;                      // [128][34] shorts
  uint8_t* dst = z ? dkb : dqb;

#pragma unroll
  for (int fr = 0; fr < 4; ++fr)
#pragma unroll
    for (int fc = 0; fc < 2; ++fc)
#pragma unroll
      for (int rg = 0; rg < 4; ++rg) {
        int row = wr * 64 + fr * 16 + g4 * 4 + rg;
        int col = wc * 32 + fc * 16 + r15;
        accs[row * 65 + col] = acc[fr][fc][rg];
      }
#pragma unroll
  for (int fr = 0; fr < 4; ++fr)
#pragma unroll
    for (int rg = 0; rg < 4; ++rg) {
      int row = wr * 64 + fr * 16 + g4 * 4 + rg;
      vsv[row * 34 + wc * 16 + r15] = f2bf(vacc[fr][rg]);
    }
  __syncthreads();

  {  // emit packed V chunks (this z covers cols z*32..z*32+31 of head by)
    const int bb = bx >> 3;
#pragma unroll
    for (int it = 0; it < 2; ++it) {
      int slot = it * 256 + t;
      int lp = slot & 63, ch = slot >> 6;      // ch 0..7
      int kl = ch & 3, ntv = ch >> 2;
      bf16x8 o;
#pragma unroll
      for (int j = 0; j < 8; ++j)
        o[j] = vsv[(kl * 32 + (lp >> 4) * 8 + j) * 34 + ntv * 16 + (lp & 15)];
      int kTg = (bx & 7) * 4 + kl;
      int ntg = z * 2 + ntv;
      size_t flat = ((((size_t)(bb * Hq + by) * 4 + ntg) * 32 + kTg) * 64 + lp) * 8;
      *reinterpret_cast<bf16x8*>(&PVout[flat]) = o;
    }
  }

#pragma unroll
  for (int pass = 0; pass < 2; ++pass) {
    {  // rope + bf16x3 split -> A-fragment planes (rows pass*64 .. +63)
      const int row = t >> 2, db = t & 3;
      const int mt = row >> 4;
      const int lfr = (row & 15) | (db << 4);
      const int rowg = pass * 64 + row;
      const int tg = (bx * 128 + rowg) & (Tq - 1);
#pragma unroll
      for (int i = 0; i < 8; ++i) {
        int d = db * 8 + i;
        float q1 = accs[rowg * 65 + d], q2 = accs[rowg * 65 + d + 32];
        float c = cosT[tg * 32 + d], s = sinT[tg * 32 + d];
        float r1 = q1 * c + q2 * s;
        float r2 = q2 * c - q1 * s;   // rms scale positive -> sign-invariant, skipped
        int i0 = ((mt * 2 + 0) * 64 + lfr) * 8 + i;
        int i1 = ((mt * 2 + 1) * 64 + lfr) * 8 + i;
        short h1 = f2bf(r1); float rr = r1 - bf2f(h1);
        short h2 = f2bf(rr); short h3 = f2bf(rr - bf2f(h2));
        RA[i0] = h1; RA[4096 + i0] = h2; RA[8192 + i0] = h3;
        h1 = f2bf(r2); rr = r2 - bf2f(h1);
        h2 = f2bf(rr); h3 = f2bf(rr - bf2f(h2));
        RA[i1] = h1; RA[4096 + i1] = h2; RA[8192 + i1] = h3;
      }
    }
    __syncthreads();
    {  // 12 MFMAs per wave: digits for 16 rows; ballot -> bytes
      const int mt = wid;
      f32x4 dacc = (f32x4){0.f, 0.f, 0.f, 0.f};
#pragma unroll
      for (int kt2 = 0; kt2 < 2; ++kt2) {
        int base = ((mt * 2 + kt2) * 64 + lane) * 8;
        bf16x8 ra0 = *reinterpret_cast<const bf16x8*>(&RA[base]);
        bf16x8 ra1 = *reinterpret_cast<const bf16x8*>(&RA[4096 + base]);
        bf16x8 ra2 = *reinterpret_cast<const bf16x8*>(&RA[8192 + base]);
        dacc = mfma16(ra0, bw0[kt2], dacc);
        dacc = mfma16(ra0, bw1[kt2], dacc);
        dacc = mfma16(ra1, bw0[kt2], dacc);
        dacc = mfma16(ra1, bw1[kt2], dacc);
        dacc = mfma16(ra0, bw2[kt2], dacc);
        dacc = mfma16(ra2, bw0[kt2], dacc);
      }
#pragma unroll
      for (int rg = 0; rg < 4; ++rg) {
        unsigned long long m = __ballot(dacc[rg] > 0.f);
        if (lane == 0) {
#pragma unroll
          for (int g2 = 0; g2 < 4; ++g2) {
            int rowg = bx * 128 + pass * 64 + mt * 16 + g2 * 4 + rg;
            uint8_t byte = (uint8_t)((m >> (g2 * 16)) & 0xFFu);
            dst[((size_t)(rowg >> 10) * Hq + by) * Tq + (rowg & (Tq - 1))] = byte;
          }
        }
      }
    }
    __syncthreads();   // protect RA before next pass / exit
  }
}

// ---- MFMA ultrametric causal attention, writes yp packed-A directly ------
__global__ __launch_bounds__(256) void attn_mfma(
    const short* __restrict__ PV, const uint8_t* __restrict__ dqb,
    const uint8_t* __restrict__ dkb, short* __restrict__ yp)
{
  __shared__ short vbuf[2][4][2][512];
  __shared__ __align__(16) uint32 dks4[256];
  __shared__ float den_lds[64];
  __shared__ short ys[64 * 66];
  const int t = threadIdx.x, wid = t >> 6, lane = t & 63;
  const int r = lane & 15, g = lane >> 4;
  const int qt = blockIdx.x, h = blockIdx.y, b = blockIdx.z;
  const int bh = b * Hq + h;
  const short* pvb = PV + ((size_t)bh * 4 + wid) * 32 * 512 + lane * 8;

  {
    const uint32* src4 = (const uint32*)(dkb + (size_t)bh * Tq);
    if (t < (qt + 1) * 16) dks4[t] = src4[t];
  }
  const uint8_t* dq_tile = dqb + (size_t)bh * Tq + qt * 64;
  uint32 myq[4];
#pragma unroll
  for (int mt = 0; mt < 4; ++mt) myq[mt] = dq_tile[mt * 16 + r];

#pragma unroll
  for (int ks = 0; ks < 2; ++ks)
    gload16(pvb + (size_t)ks * 512, &vbuf[0][wid][ks][0]);

  f32x4 acc[4];
#pragma unroll
  for (int mt = 0; mt < 4; ++mt) acc[mt] = (f32x4){0.f, 0.f, 0.f, 0.f};
  uint32 den_i = 0;

  auto tile = [&](int kt, int db, bool MASK) {
    __builtin_amdgcn_s_setprio(1);
    bf16x8 bfr[2];
#pragma unroll
    for (int ks = 0; ks < 2; ++ks)
      bfr[ks] = *reinterpret_cast<const bf16x8*>(&vbuf[db][wid][ks][lane * 8]);
    unsigned long long d8[2];
#pragma unroll
    for (int ks = 0; ks < 2; ++ks)
      d8[ks] = *reinterpret_cast<const unsigned long long*>(
          (const char*)dks4 + kt * 64 + ks * 32 + g * 8);
#pragma unroll
    for (int mt = 0; mt < 4; ++mt) {
      const uint32 dq = myq[mt];
      const int qrow = mt * 16 + r;
#pragma unroll
      for (int ks = 0; ks < 2; ++ks) {
        const int kbase = ks * 32 + g * 8;
        uint32 parts[4];
#pragma unroll
        for (int jj = 0; jj < 4; ++jj) {
          uint32 b0 = (uint32)(d8[ks] >> (16 * jj)) & 0xFFu;
          uint32 b1 = (uint32)(d8[ks] >> (16 * jj + 8)) & 0xFFu;
          uint32 e0 = (uint32)__builtin_ctz((dq ^ b0) | 0x100u);
          uint32 e1 = (uint32)__builtin_ctz((dq ^ b1) | 0x100u);
          uint32 w0 = 0x3F80u + (e0 << 7);
          uint32 w1 = 0x3F80u + (e1 << 7);
          if (MASK) {
            if (kbase + 2 * jj     > qrow) w0 = 0;
            if (kbase + 2 * jj + 1 > qrow) w1 = 0;
          }
          if (mt == wid) {
            den_i += (w0 ? (1u << e0) : 0u);
            den_i += (w1 ? (1u << e1) : 0u);
          }
          parts[jj] = w0 | (w1 << 16);
        }
        union { uint32 u[4]; bf16x8 v8; } cv;
        cv.u[0] = parts[0]; cv.u[1] = parts[1];
        cv.u[2] = parts[2]; cv.u[3] = parts[3];
        acc[mt] = mfma16(cv.v8, bfr[ks], acc[mt]);
      }
    }
    __builtin_amdgcn_s_setprio(0);
  };

  int cur = 0;
  for (int kt = 0; kt < qt; ++kt) {
    __syncthreads();
#pragma unroll
    for (int ks = 0; ks < 2; ++ks)
      gload16(pvb + (size_t)((kt + 1) * 2 + ks) * 512, &vbuf[cur ^ 1][wid][ks][0]);
    tile(kt, cur, false);
    cur ^= 1;
  }
  __syncthreads();
  tile(qt, cur, true);

  den_i += (uint32)__shfl_xor((int)den_i, 16, 64);
  den_i += (uint32)__shfl_xor((int)den_i, 32, 64);
  if (lane < 16) den_lds[wid * 16 + lane] = (float)den_i;
  __syncthreads();

  const int dglob = wid * 16 + r;
#pragma unroll
  for (int mt = 0; mt < 4; ++mt)
#pragma unroll
    for (int rg = 0; rg < 4; ++rg) {
      int qloc = mt * 16 + g * 4 + rg;
      ys[qloc * 66 + dglob] = f2bf(acc[mt][rg] / fmaxf(den_lds[qloc], 1e-9f));
    }
  __syncthreads();
#pragma unroll
  for (int it = 0; it < 2; ++it) {
    int slot = it * 256 + t;
    int lp = slot & 63, ch = slot >> 6;
    int kh = ch & 1, mtl = ch >> 1;
    int fbase = kh * 32 + (lp >> 4) * 8;
    bf16x8 o;
#pragma unroll
    for (int j = 0; j < 8; ++j) o[j] = ys[(mtl * 16 + (lp & 15)) * 66 + fbase + j];
    int mtg = b * 64 + qt * 4 + mtl;
    int ktg = h * 2 + kh;
    size_t flat = ((size_t)mtg * 32 + ktg) * 512 + (size_t)lp * 8;
    *reinterpret_cast<bf16x8*>(&yp[flat]) = o;
  }
}

// ---- proj GEMM: 64x64 tile, BK=64 stages, 512 blocks (2/CU) --------------
__global__ __launch_bounds__(256) void gemm_proj(
    const short* __restrict__ A0, const short* __restrict__ B0,
    float* __restrict__ C, int M, int N, int K)
{
  constexpr int BUF = 16 * 512;
  __shared__ short sm[2 * BUF];               // 32 KB
  const int t = threadIdx.x, wid = t >> 6, lane = t & 63;
  const int bx = blockIdx.x, by = blockIdx.y;
  const int KT = K >> 5;                      // 32
  const int NST = KT >> 1;                    // 16 stages of BK=64

  const short* gb[4]; int lof[4];
#pragma unroll
  for (int i = 0; i < 4; ++i) {
    int c = wid * 4 + i;
    if (c < 8) {
      int mt = bx * 4 + (c >> 1), kt = c & 1;
      gb[i] = A0 + ((size_t)(mt * KT + kt) * 64 + lane) * 8;
    } else {
      int c2 = c - 8;
      int nt = by * 4 + (c2 >> 1), kt = c2 & 1;
      gb[i] = B0 + ((size_t)(nt * KT + kt) * 64 + lane) * 8;
    }
    lof[i] = c * 512;
  }

  f32x4 acc[4];
#pragma unroll
  for (int nt = 0; nt < 4; ++nt) acc[nt] = (f32x4){0.f, 0.f, 0.f, 0.f};

#pragma unroll
  for (int i = 0; i < 4; ++i) gload16(gb[i], &sm[lof[i]]);

  int cur = 0;
  for (int s = 0; s < NST; ++s) {
    __syncthreads();
    if (s + 1 < NST) {
#pragma unroll
      for (int i = 0; i < 4; ++i)
        gload16(gb[i] + (size_t)(s + 1) * 1024, &sm[(cur ^ 1) * BUF + lof[i]]);
    }
    const short* sa = &sm[cur * BUF];
#pragma unroll
    for (int kt2 = 0; kt2 < 2; ++kt2) {
      bf16x8 af = *reinterpret_cast<const bf16x8*>(sa + (wid * 2 + kt2) * 512 + lane * 8);
#pragma unroll
      for (int nt = 0; nt < 4; ++nt) {
        bf16x8 bf_ = *reinterpret_cast<const bf16x8*>(sa + (8 + nt * 2 + kt2) * 512 + lane * 8);
        acc[nt] = mfma16(af, bf_, acc[nt]);
      }
    }
    cur ^= 1;
  }

  const int rb = bx * 64 + wid * 16 + ((lane >> 4) << 2);
  const int cb = by * 64 + (lane & 15);
#pragma unroll
  for (int nt = 0; nt < 4; ++nt)
#pragma unroll
    for (int rg = 0; rg < 4; ++rg)
      C[(size_t)(rb + rg) * N + cb + nt * 16] = acc[nt][rg];
}

// --------------------------------------------------------------------------
extern "C" void kernel_launch(void* const* d_in, const int* in_sizes, int n_in,
                              void* d_out, int out_size, void* d_ws, size_t ws_size,
                              hipStream_t stream)
{
  const float* x    = (const float*)d_in[0];
  const float* cosT = (const float*)d_in[1];
  const float* sinT = (const float*)d_in[2];
  const float* Wq   = (const float*)d_in[3];
  const float* Wk   = (const float*)d_in[4];
  const float* Wv   = (const float*)d_in[5];
  const float* Wpr  = (const float*)d_in[6];
  const float* Wdq  = (const float*)d_in[7];
  const float* Wdk  = (const float*)d_in[8];
  float* out = (float*)d_out;

  const size_t MB = (size_t)1 << 20;
  char* w = (char*)d_ws;
  short* PV  = (short*)(w + 0 * MB);
  short* yp  = (short*)(w + 8 * MB);
  short* xp0 = (short*)(w + 24 * MB);
  short* xp1 = (short*)(w + 28 * MB);
  short* xp2 = (short*)(w + 32 * MB);
  short* wq0 = (short*)(w + 36 * MB);
  short* wq1 = (short*)(w + 38 * MB);
  short* wq2 = (short*)(w + 40 * MB);
  short* wk0 = (short*)(w + 42 * MB);
  short* wk1 = (short*)(w + 44 * MB);
  short* wk2 = (short*)(w + 46 * MB);
  short* wv_ = (short*)(w + 48 * MB);
  short* wp_ = (short*)(w + 50 * MB);
  uint8_t* dqb = (uint8_t*)(w + 52 * MB);
  uint8_t* dkb = dqb + (size_t)Bq * Hq * Tq;

  const int M = Bq * Tq, N = Cq, K = Cq;

  prep_all<<<2048, 256, 0, stream>>>(
      x, Wq, Wk, Wv, Wpr, xp0, xp1, xp2,
      wq0, wq1, wq2, wk0, wk1, wk2, wv_, wp_, N, K);

  gemm_qk_digits<<<dim3(16, 16, 2), 256, 0, stream>>>(
      xp0, xp1, xp2, wq0, wq1, wq2, wk0, wk1, wk2, wv_,
      cosT, sinT, Wdq, Wdk, dqb, dkb, PV, K);

  attn_mfma<<<dim3(16, 16, 2), 256, 0, stream>>>(PV, dqb, dkb, yp);

  gemm_proj<<<dim3(32, 16), 256, 0, stream>>>(yp, wp_, out, M, N, K);
}

// Round 15
// 100.759 us; speedup vs baseline: 1.2047x; 1.0910x over previous
//
#include <hip/hip_runtime.h>
#include <stdint.h>

#define Bq 2
#define Tq 1024
#define Cq 1024
#define Hq 16
#define HDq 64

typedef unsigned int uint32;
typedef __attribute__((ext_vector_type(8))) short bf16x8;
typedef __attribute__((ext_vector_type(4))) float f32x4;

__device__ __forceinline__ short f2bf(float x) {
  union { float f; uint32 u; } v; v.f = x;
  uint32 r = (v.u + 0x7FFFu + ((v.u >> 16) & 1u)) >> 16;
  return (short)r;
}
__device__ __forceinline__ float bf2f(short h) {
  union { uint32 u; float f; } v; v.u = ((uint32)(unsigned short)h) << 16;
  return v.f;
}
__device__ __forceinline__ void gload16(const short* g, short* l) {
  __builtin_amdgcn_global_load_lds(
      (const __attribute__((address_space(1))) unsigned int*)g,
      (__attribute__((address_space(3))) unsigned int*)l, 16, 0, 0);
}
__device__ __forceinline__ f32x4 mfma16(bf16x8 a, bf16x8 b, f32x4 c) {
  return __builtin_amdgcn_mfma_f32_16x16x32_bf16(a, b, c, 0, 0, 0);
}

// ---- prep: pack x rows (blocks 0..1023) + split all 4 W mats (1024..2047) -
__global__ __launch_bounds__(256) void prep_all(
    const float* __restrict__ x,
    const float* __restrict__ Wq, const float* __restrict__ Wk,
    const float* __restrict__ Wv, const float* __restrict__ Wp,
    short* __restrict__ xp0, short* __restrict__ xp1, short* __restrict__ xp2,
    short* __restrict__ q0, short* __restrict__ q1, short* __restrict__ q2,
    short* __restrict__ k0, short* __restrict__ k1, short* __restrict__ k2,
    short* __restrict__ v0, short* __restrict__ p0, int N, int K)
{
  __shared__ float ws_[64][65];
  const int t = threadIdx.x;
  const int bid = blockIdx.x;
  const int KT = K >> 5;

  if (bid < 1024) {          // ---- pack_rows<3> on x ----
    const int tg = bid * 256 + t;
    const int lane = tg & 63, chunk = tg >> 6;
    const int mt = chunk / KT, kt = chunk % KT;
    const int m = mt * 16 + (lane & 15);
    const int k = kt * 32 + ((lane >> 4) << 3);
    float4 v0v = *reinterpret_cast<const float4*>(&x[(size_t)m * K + k]);
    float4 v1v = *reinterpret_cast<const float4*>(&x[(size_t)m * K + k + 4]);
    float a[8] = {v0v.x, v0v.y, v0v.z, v0v.w, v1v.x, v1v.y, v1v.z, v1v.w};
    bf16x8 o0, o1, o2;
#pragma unroll
    for (int j = 0; j < 8; ++j) {
      short h1 = f2bf(a[j]); o0[j] = h1;
      float r1 = a[j] - bf2f(h1);
      short h2 = f2bf(r1); o1[j] = h2;
      o2[j] = f2bf(r1 - bf2f(h2));
    }
    size_t off = (size_t)tg * 8;
    *reinterpret_cast<bf16x8*>(&xp0[off]) = o0;
    *reinterpret_cast<bf16x8*>(&xp1[off]) = o1;
    *reinterpret_cast<bf16x8*>(&xp2[off]) = o2;
    return;
  }
  const int id = bid - 1024;
  const int z = id >> 8, rem = id & 255;
  const int bxp = rem & 15, byp = rem >> 4;
  const float* W = (z == 0) ? Wq : (z == 1) ? Wk : (z == 2) ? Wv : Wp;
  short* P0 = (z == 0) ? q0 : (z == 1) ? k0 : (z == 2) ? v0 : p0;
  short* P1 = (z == 0) ? q1 : k1;
  short* P2 = (z == 0) ? q2 : k2;
  const bool ns3 = (z < 2);
  const int n0 = bxp * 64, k0g = byp * 64;
#pragma unroll
  for (int pass = 0; pass < 4; ++pass) {
    int f = pass * 256 + t;
    int r = f >> 4, c4 = (f & 15) << 2;
    float4 vv = *reinterpret_cast<const float4*>(&W[(size_t)(k0g + r) * N + n0 + c4]);
    ws_[r][c4 + 0] = vv.x; ws_[r][c4 + 1] = vv.y;
    ws_[r][c4 + 2] = vv.z; ws_[r][c4 + 3] = vv.w;
  }
  __syncthreads();
#pragma unroll
  for (int s = 0; s < 2; ++s) {
    int slot = s * 256 + t;
    int lane = slot & 63, u = slot >> 6;
    int ntl = u >> 1, ktl = u & 1;
    int nl = ntl * 16 + (lane & 15);
    int kb = ktl * 32 + ((lane >> 4) << 3);
    bf16x8 o0, o1, o2;
#pragma unroll
    for (int j = 0; j < 8; ++j) {
      float a = ws_[kb + j][nl];
      short h1 = f2bf(a); o0[j] = h1;
      float r1 = a - bf2f(h1);
      short h2 = f2bf(r1); o1[j] = h2;
      o2[j] = f2bf(r1 - bf2f(h2));
    }
    size_t nt = (size_t)bxp * 4 + ntl;
    size_t kt = (size_t)byp * 2 + ktl;
    size_t off = ((nt * KT + kt) * 64 + lane) * 8;
    *reinterpret_cast<bf16x8*>(&P0[off]) = o0;
    if (ns3) {
      *reinterpret_cast<bf16x8*>(&P1[off]) = o1;
      *reinterpret_cast<bf16x8*>(&P2[off]) = o2;
    }
  }
}

// ---- q/k GEMM (bf16x3) + fused V half + rope+digit MFMA epilogue ---------
// by = head. z=0: q digits + V cols [0,32); z=1: k digits + V cols [32,64).
__global__ __launch_bounds__(256) void gemm_qk_digits(
    const short* __restrict__ A0, const short* __restrict__ A1, const short* __restrict__ A2,
    const short* __restrict__ Bq0, const short* __restrict__ Bq1, const short* __restrict__ Bq2,
    const short* __restrict__ Bk0, const short* __restrict__ Bk1, const short* __restrict__ Bk2,
    const short* __restrict__ Bv0,
    const float* __restrict__ cosT, const float* __restrict__ sinT,
    const float* __restrict__ Wdq, const float* __restrict__ Wdk,
    uint8_t* __restrict__ dqb, uint8_t* __restrict__ dkb,
    short* __restrict__ PVout, int K)
{
  constexpr int NS = 3;
  constexpr int BUF = 38 * 512;               // 24 A + 12 Bqk + 2 Bv chunks
  __shared__ short sm[2 * BUF];               // 77824 B
  const int t = threadIdx.x, wid = t >> 6, lane = t & 63;
  const int wr = wid >> 1, wc = wid & 1;
  const int g4 = lane >> 4, r15 = lane & 15;
  const int bx = blockIdx.x, by = blockIdx.y, z = blockIdx.z;
  const int KT = K >> 5;
  const short* Ap[3] = {A0, A1, A2};
  const short* Bp[3];
  if (z == 0) { Bp[0] = Bq0; Bp[1] = Bq1; Bp[2] = Bq2; }
  else        { Bp[0] = Bk0; Bp[1] = Bk1; Bp[2] = Bk2; }

  const short* gb[9]; int lof[9];
#pragma unroll
  for (int i = 0; i < 9; ++i) {
    int c = wid * 9 + i;
    if (c < 24) {
      int p = c >> 3, mtl = c & 7;
      gb[i] = Ap[p] + ((size_t)(bx * 8 + mtl) * KT * 512 + lane * 8);
      lof[i] = c * 512;
    } else {
      int c2 = c - 24; int p = c2 >> 2, ntl = c2 & 3;
      gb[i] = Bp[p] + ((size_t)(by * 4 + ntl) * KT * 512 + lane * 8);
      lof[i] = (24 + c2) * 512;
    }
  }
  const short* gbv = nullptr; int lofv = 0;
  if (wid < 2) {
    gbv = Bv0 + ((size_t)(by * 4 + z * 2 + wid) * KT * 512 + lane * 8);
    lofv = (36 + wid) * 512;
  }

  f32x4 acc[4][2], vacc[4];
#pragma unroll
  for (int fr = 0; fr < 4; ++fr) {
#pragma unroll
    for (int fc = 0; fc < 2; ++fc) acc[fr][fc] = (f32x4){0.f, 0.f, 0.f, 0.f};
    vacc[fr] = (f32x4){0.f, 0.f, 0.f, 0.f};
  }

#pragma unroll
  for (int i = 0; i < 9; ++i) gload16(gb[i], &sm[lof[i]]);
  if (wid < 2) gload16(gbv, &sm[lofv]);

  int cur = 0;
  for (int kt = 0; kt < KT; ++kt) {
    __syncthreads();
    if (kt + 1 < KT) {
#pragma unroll
      for (int i = 0; i < 9; ++i)
        gload16(gb[i] + (size_t)(kt + 1) * 512, &sm[(cur ^ 1) * BUF + lof[i]]);
      if (wid < 2)
        gload16(gbv + (size_t)(kt + 1) * 512, &sm[(cur ^ 1) * BUF + lofv]);
    }
    const short* sa = &sm[cur * BUF];
    const short* sbb = sa + 24 * 512;
    bf16x8 af[NS][4], bfr[NS][2];
#pragma unroll
    for (int p = 0; p < NS; ++p)
#pragma unroll
      for (int fr = 0; fr < 4; ++fr)
        af[p][fr] = *reinterpret_cast<const bf16x8*>(sa + (p * 8 + wr * 4 + fr) * 512 + lane * 8);
#pragma unroll
    for (int p = 0; p < NS; ++p)
#pragma unroll
      for (int fc = 0; fc < 2; ++fc)
        bfr[p][fc] = *reinterpret_cast<const bf16x8*>(sbb + (p * 4 + wc * 2 + fc) * 512 + lane * 8);
    bf16x8 bv = *reinterpret_cast<const bf16x8*>(sa + (36 + wc) * 512 + lane * 8);
#pragma unroll
    for (int fr = 0; fr < 4; ++fr) {
#pragma unroll
      for (int fc = 0; fc < 2; ++fc) {
        acc[fr][fc] = mfma16(af[0][fr], bfr[0][fc], acc[fr][fc]);
        acc[fr][fc] = mfma16(af[0][fr], bfr[1][fc], acc[fr][fc]);
        acc[fr][fc] = mfma16(af[1][fr], bfr[0][fc], acc[fr][fc]);
        acc[fr][fc] = mfma16(af[1][fr], bfr[1][fc], acc[fr][fc]);
        acc[fr][fc] = mfma16(af[0][fr], bfr[2][fc], acc[fr][fc]);
        acc[fr][fc] = mfma16(af[2][fr], bfr[0][fc], acc[fr][fc]);
      }
      vacc[fr] = mfma16(af[0][fr], bv, vacc[fr]);
    }
    cur ^= 1;
  }

  // ---- epilogue ----------------------------------------------------------
  __syncthreads();   // all LDS reads of sm done; repurpose
  const float* Wd = z ? Wdk : Wdq;
  bf16x8 bw0[2], bw1[2], bw2[2];
#pragma unroll
  for (int kt2 = 0; kt2 < 2; ++kt2) {
#pragma unroll
    for (int j = 0; j < 8; ++j) {
      float wv = (r15 < 8) ? Wd[(size_t)(kt2 * 32 + g4 * 8 + j) * 8 + r15] : 0.f;
      short h1 = f2bf(wv); float rr = wv - bf2f(h1);
      short h2 = f2bf(rr); short h3 = f2bf(rr - bf2f(h2));
      bw0[kt2][j] = h1; bw1[kt2][j] = h2; bw2[kt2][j] = h3;
    }
  }
  float* accs = reinterpret_cast<float*>(sm);   // [128][65] f32 (16640 shorts)
  short* RA  = sm + 16640;                      // 3 x 4096 shorts
  short* vsv = sm + 28928;                      // [128][34] shorts
  uint8_t* dst = z ? dkb : dqb;

#pragma unroll
  for (int fr = 0; fr < 4; ++fr)
#pragma unroll
    for (int fc = 0; fc < 2; ++fc)
#pragma unroll
      for (int rg = 0; rg < 4; ++rg) {
        int row = wr * 64 + fr * 16 + g4 * 4 + rg;
        int col = wc * 32 + fc * 16 + r15;
        accs[row * 65 + col] = acc[fr][fc][rg];
      }
#pragma unroll
  for (int fr = 0; fr < 4; ++fr)
#pragma unroll
    for (int rg = 0; rg < 4; ++rg) {
      int row = wr * 64 + fr * 16 + g4 * 4 + rg;
      vsv[row * 34 + wc * 16 + r15] = f2bf(vacc[fr][rg]);
    }
  __syncthreads();

  {  // emit packed V chunks (this z covers cols z*32..z*32+31 of head by)
    const int bb = bx >> 3;
#pragma unroll
    for (int it = 0; it < 2; ++it) {
      int slot = it * 256 + t;
      int lp = slot & 63, ch = slot >> 6;      // ch 0..7
      int kl = ch & 3, ntv = ch >> 2;
      bf16x8 o;
#pragma unroll
      for (int j = 0; j < 8; ++j)
        o[j] = vsv[(kl * 32 + (lp >> 4) * 8 + j) * 34 + ntv * 16 + (lp & 15)];
      int kTg = (bx & 7) * 4 + kl;
      int ntg = z * 2 + ntv;
      size_t flat = ((((size_t)(bb * Hq + by) * 4 + ntg) * 32 + kTg) * 64 + lp) * 8;
      *reinterpret_cast<bf16x8*>(&PVout[flat]) = o;
    }
  }

#pragma unroll
  for (int pass = 0; pass < 2; ++pass) {
    {  // rope + bf16x3 split -> A-fragment planes (rows pass*64 .. +63)
      const int row = t >> 2, db = t & 3;
      const int mt = row >> 4;
      const int lfr = (row & 15) | (db << 4);
      const int rowg = pass * 64 + row;
      const int tg = (bx * 128 + rowg) & (Tq - 1);
#pragma unroll
      for (int i = 0; i < 8; ++i) {
        int d = db * 8 + i;
        float q1 = accs[rowg * 65 + d], q2 = accs[rowg * 65 + d + 32];
        float c = cosT[tg * 32 + d], s = sinT[tg * 32 + d];
        float r1 = q1 * c + q2 * s;
        float r2 = q2 * c - q1 * s;   // rms scale positive -> sign-invariant, skipped
        int i0 = ((mt * 2 + 0) * 64 + lfr) * 8 + i;
        int i1 = ((mt * 2 + 1) * 64 + lfr) * 8 + i;
        short h1 = f2bf(r1); float rr = r1 - bf2f(h1);
        short h2 = f2bf(rr); short h3 = f2bf(rr - bf2f(h2));
        RA[i0] = h1; RA[4096 + i0] = h2; RA[8192 + i0] = h3;
        h1 = f2bf(r2); rr = r2 - bf2f(h1);
        h2 = f2bf(rr); h3 = f2bf(rr - bf2f(h2));
        RA[i1] = h1; RA[4096 + i1] = h2; RA[8192 + i1] = h3;
      }
    }
    __syncthreads();
    {  // 12 MFMAs per wave: digits for 16 rows; ballot -> bytes
      const int mt = wid;
      f32x4 dacc = (f32x4){0.f, 0.f, 0.f, 0.f};
#pragma unroll
      for (int kt2 = 0; kt2 < 2; ++kt2) {
        int base = ((mt * 2 + kt2) * 64 + lane) * 8;
        bf16x8 ra0 = *reinterpret_cast<const bf16x8*>(&RA[base]);
        bf16x8 ra1 = *reinterpret_cast<const bf16x8*>(&RA[4096 + base]);
        bf16x8 ra2 = *reinterpret_cast<const bf16x8*>(&RA[8192 + base]);
        dacc = mfma16(ra0, bw0[kt2], dacc);
        dacc = mfma16(ra0, bw1[kt2], dacc);
        dacc = mfma16(ra1, bw0[kt2], dacc);
        dacc = mfma16(ra1, bw1[kt2], dacc);
        dacc = mfma16(ra0, bw2[kt2], dacc);
        dacc = mfma16(ra2, bw0[kt2], dacc);
      }
#pragma unroll
      for (int rg = 0; rg < 4; ++rg) {
        unsigned long long m = __ballot(dacc[rg] > 0.f);
        if (lane == 0) {
#pragma unroll
          for (int g2 = 0; g2 < 4; ++g2) {
            int rowg = bx * 128 + pass * 64 + mt * 16 + g2 * 4 + rg;
            uint8_t byte = (uint8_t)((m >> (g2 * 16)) & 0xFFu);
            dst[((size_t)(rowg >> 10) * Hq + by) * Tq + (rowg & (Tq - 1))] = byte;
          }
        }
      }
    }
    __syncthreads();   // protect RA before next pass / exit
  }
}

// ---- MFMA ultrametric causal attention, writes yp packed-A directly ------
// Load balance: work per block ~ qt+1; a CU hosts the same (x,y) for b=0,1,
// so reflect qt for b=1 -> per-CU work is the constant (x+1)+(16-x) = 17.
__global__ __launch_bounds__(256) void attn_mfma(
    const short* __restrict__ PV, const uint8_t* __restrict__ dqb,
    const uint8_t* __restrict__ dkb, short* __restrict__ yp)
{
  __shared__ short vbuf[2][4][2][512];
  __shared__ __align__(16) uint32 dks4[256];
  __shared__ float den_lds[64];
  __shared__ short ys[64 * 66];
  const int t = threadIdx.x, wid = t >> 6, lane = t & 63;
  const int r = lane & 15, g = lane >> 4;
  const int h = blockIdx.y, b = blockIdx.z;
  const int qt = b ? (15 - blockIdx.x) : blockIdx.x;   // balance across b
  const int bh = b * Hq + h;
  const short* pvb = PV + ((size_t)bh * 4 + wid) * 32 * 512 + lane * 8;

  {
    const uint32* src4 = (const uint32*)(dkb + (size_t)bh * Tq);
    if (t < (qt + 1) * 16) dks4[t] = src4[t];
  }
  const uint8_t* dq_tile = dqb + (size_t)bh * Tq + qt * 64;
  uint32 myq[4];
#pragma unroll
  for (int mt = 0; mt < 4; ++mt) myq[mt] = dq_tile[mt * 16 + r];

#pragma unroll
  for (int ks = 0; ks < 2; ++ks)
    gload16(pvb + (size_t)ks * 512, &vbuf[0][wid][ks][0]);

  f32x4 acc[4];
#pragma unroll
  for (int mt = 0; mt < 4; ++mt) acc[mt] = (f32x4){0.f, 0.f, 0.f, 0.f};
  uint32 den_i = 0;

  auto tile = [&](int kt, int db, bool MASK) {
    __builtin_amdgcn_s_setprio(1);
    bf16x8 bfr[2];
#pragma unroll
    for (int ks = 0; ks < 2; ++ks)
      bfr[ks] = *reinterpret_cast<const bf16x8*>(&vbuf[db][wid][ks][lane * 8]);
    unsigned long long d8[2];
#pragma unroll
    for (int ks = 0; ks < 2; ++ks)
      d8[ks] = *reinterpret_cast<const unsigned long long*>(
          (const char*)dks4 + kt * 64 + ks * 32 + g * 8);
#pragma unroll
    for (int mt = 0; mt < 4; ++mt) {
      const uint32 dq = myq[mt];
      const int qrow = mt * 16 + r;
#pragma unroll
      for (int ks = 0; ks < 2; ++ks) {
        const int kbase = ks * 32 + g * 8;
        uint32 parts[4];
#pragma unroll
        for (int jj = 0; jj < 4; ++jj) {
          uint32 b0 = (uint32)(d8[ks] >> (16 * jj)) & 0xFFu;
          uint32 b1 = (uint32)(d8[ks] >> (16 * jj + 8)) & 0xFFu;
          uint32 e0 = (uint32)__builtin_ctz((dq ^ b0) | 0x100u);
          uint32 e1 = (uint32)__builtin_ctz((dq ^ b1) | 0x100u);
          uint32 w0 = 0x3F80u + (e0 << 7);
          uint32 w1 = 0x3F80u + (e1 << 7);
          if (MASK) {
            if (kbase + 2 * jj     > qrow) w0 = 0;
            if (kbase + 2 * jj + 1 > qrow) w1 = 0;
          }
          if (mt == wid) {
            den_i += (w0 ? (1u << e0) : 0u);
            den_i += (w1 ? (1u << e1) : 0u);
          }
          parts[jj] = w0 | (w1 << 16);
        }
        union { uint32 u[4]; bf16x8 v8; } cv;
        cv.u[0] = parts[0]; cv.u[1] = parts[1];
        cv.u[2] = parts[2]; cv.u[3] = parts[3];
        acc[mt] = mfma16(cv.v8, bfr[ks], acc[mt]);
      }
    }
    __builtin_amdgcn_s_setprio(0);
  };

  int cur = 0;
  for (int kt = 0; kt < qt; ++kt) {
    __syncthreads();
#pragma unroll
    for (int ks = 0; ks < 2; ++ks)
      gload16(pvb + (size_t)((kt + 1) * 2 + ks) * 512, &vbuf[cur ^ 1][wid][ks][0]);
    tile(kt, cur, false);
    cur ^= 1;
  }
  __syncthreads();
  tile(qt, cur, true);

  den_i += (uint32)__shfl_xor((int)den_i, 16, 64);
  den_i += (uint32)__shfl_xor((int)den_i, 32, 64);
  if (lane < 16) den_lds[wid * 16 + lane] = (float)den_i;
  __syncthreads();

  const int dglob = wid * 16 + r;
#pragma unroll
  for (int mt = 0; mt < 4; ++mt)
#pragma unroll
    for (int rg = 0; rg < 4; ++rg) {
      int qloc = mt * 16 + g * 4 + rg;
      ys[qloc * 66 + dglob] = f2bf(acc[mt][rg] / fmaxf(den_lds[qloc], 1e-9f));
    }
  __syncthreads();
#pragma unroll
  for (int it = 0; it < 2; ++it) {
    int slot = it * 256 + t;
    int lp = slot & 63, ch = slot >> 6;
    int kh = ch & 1, mtl = ch >> 1;
    int fbase = kh * 32 + (lp >> 4) * 8;
    bf16x8 o;
#pragma unroll
    for (int j = 0; j < 8; ++j) o[j] = ys[(mtl * 16 + (lp & 15)) * 66 + fbase + j];
    int mtg = b * 64 + qt * 4 + mtl;
    int ktg = h * 2 + kh;
    size_t flat = ((size_t)mtg * 32 + ktg) * 512 + (size_t)lp * 8;
    *reinterpret_cast<bf16x8*>(&yp[flat]) = o;
  }
}

// ---- proj GEMM: 64x64 tile, BK=64 stages, 512 blocks (2/CU) --------------
__global__ __launch_bounds__(256) void gemm_proj(
    const short* __restrict__ A0, const short* __restrict__ B0,
    float* __restrict__ C, int M, int N, int K)
{
  constexpr int BUF = 16 * 512;
  __shared__ short sm[2 * BUF];               // 32 KB
  const int t = threadIdx.x, wid = t >> 6, lane = t & 63;
  const int bx = blockIdx.x, by = blockIdx.y;
  const int KT = K >> 5;                      // 32
  const int NST = KT >> 1;                    // 16 stages of BK=64

  const short* gb[4]; int lof[4];
#pragma unroll
  for (int i = 0; i < 4; ++i) {
    int c = wid * 4 + i;
    if (c < 8) {
      int mt = bx * 4 + (c >> 1), kt = c & 1;
      gb[i] = A0 + ((size_t)(mt * KT + kt) * 64 + lane) * 8;
    } else {
      int c2 = c - 8;
      int nt = by * 4 + (c2 >> 1), kt = c2 & 1;
      gb[i] = B0 + ((size_t)(nt * KT + kt) * 64 + lane) * 8;
    }
    lof[i] = c * 512;
  }

  f32x4 acc[4];
#pragma unroll
  for (int nt = 0; nt < 4; ++nt) acc[nt] = (f32x4){0.f, 0.f, 0.f, 0.f};

#pragma unroll
  for (int i = 0; i < 4; ++i) gload16(gb[i], &sm[lof[i]]);

  int cur = 0;
  for (int s = 0; s < NST; ++s) {
    __syncthreads();
    if (s + 1 < NST) {
#pragma unroll
      for (int i = 0; i < 4; ++i)
        gload16(gb[i] + (size_t)(s + 1) * 1024, &sm[(cur ^ 1) * BUF + lof[i]]);
    }
    const short* sa = &sm[cur * BUF];
#pragma unroll
    for (int kt2 = 0; kt2 < 2; ++kt2) {
      bf16x8 af = *reinterpret_cast<const bf16x8*>(sa + (wid * 2 + kt2) * 512 + lane * 8);
#pragma unroll
      for (int nt = 0; nt < 4; ++nt) {
        bf16x8 bf_ = *reinterpret_cast<const bf16x8*>(sa + (8 + nt * 2 + kt2) * 512 + lane * 8);
        acc[nt] = mfma16(af, bf_, acc[nt]);
      }
    }
    cur ^= 1;
  }

  const int rb = bx * 64 + wid * 16 + ((lane >> 4) << 2);
  const int cb = by * 64 + (lane & 15);
#pragma unroll
  for (int nt = 0; nt < 4; ++nt)
#pragma unroll
    for (int rg = 0; rg < 4; ++rg)
      C[(size_t)(rb + rg) * N + cb + nt * 16] = acc[nt][rg];
}

// --------------------------------------------------------------------------
extern "C" void kernel_launch(void* const* d_in, const int* in_sizes, int n_in,
                              void* d_out, int out_size, void* d_ws, size_t ws_size,
                              hipStream_t stream)
{
  const float* x    = (const float*)d_in[0];
  const float* cosT = (const float*)d_in[1];
  const float* sinT = (const float*)d_in[2];
  const float* Wq   = (const float*)d_in[3];
  const float* Wk   = (const float*)d_in[4];
  const float* Wv   = (const float*)d_in[5];
  const float* Wpr  = (const float*)d_in[6];
  const float* Wdq  = (const float*)d_in[7];
  const float* Wdk  = (const float*)d_in[8];
  float* out = (float*)d_out;

  const size_t MB = (size_t)1 << 20;
  char* w = (char*)d_ws;
  short* PV  = (short*)(w + 0 * MB);
  short* yp  = (short*)(w + 8 * MB);
  short* xp0 = (short*)(w + 24 * MB);
  short* xp1 = (short*)(w + 28 * MB);
  short* xp2 = (short*)(w + 32 * MB);
  short* wq0 = (short*)(w + 36 * MB);
  short* wq1 = (short*)(w + 38 * MB);
  short* wq2 = (short*)(w + 40 * MB);
  short* wk0 = (short*)(w + 42 * MB);
  short* wk1 = (short*)(w + 44 * MB);
  short* wk2 = (short*)(w + 46 * MB);
  short* wv_ = (short*)(w + 48 * MB);
  short* wp_ = (short*)(w + 50 * MB);
  uint8_t* dqb = (uint8_t*)(w + 52 * MB);
  uint8_t* dkb = dqb + (size_t)Bq * Hq * Tq;

  const int M = Bq * Tq, N = Cq, K = Cq;

  prep_all<<<2048, 256, 0, stream>>>(
      x, Wq, Wk, Wv, Wpr, xp0, xp1, xp2,
      wq0, wq1, wq2, wk0, wk1, wk2, wv_, wp_, N, K);

  gemm_qk_digits<<<dim3(16, 16, 2), 256, 0, stream>>>(
      xp0, xp1, xp2, wq0, wq1, wq2, wk0, wk1, wk2, wv_,
      cosT, sinT, Wdq, Wdk, dqb, dkb, PV, K);

  attn_mfma<<<dim3(16, 16, 2), 256, 0, stream>>>(PV, dqb, dkb, yp);

  gemm_proj<<<dim3(32, 16), 256, 0, stream>>>(yp, wp_, out, M, N, K);
}